// Round 23
// baseline (23.686 us; speedup 1.0000x reference)
//
#include <hip/hip_runtime.h>
#include <math.h>

#define KK 20
#define NPTS 8192
#define NQB 8               // queries per block (= 1 per wave)
#define QPL 8               // queries per lane (pass 1), as 4 packed pairs
#define NCH 512             // half-chunks per query (16 pts: 4 windows x 4)
#define THREADS 512
#define WIN 2048
#define NWIN 4
#define JPW 4               // consecutive points per half-chunk per window
#define CAP 64              // hit buffer capacity per query
#define MAXC 64             // candidate-chunk list capacity per query
#define MARGIN 4e-3f        // >> 2*max|d_fast - d_exact| + 22-bit-T overshoot slack

typedef float v2f __attribute__((ext_vector_type(2)));

// Exact (non-contracted) IEEE ops matching the NumPy reference bit-for-bit.
// np.sum (pairwise, n<8) accumulates ascending: (x^2 + y^2) + z^2.
__device__ __forceinline__ float norm3(float x, float y, float z) {
    return __fadd_rn(__fadd_rn(__fmul_rn(x, x), __fmul_rn(y, y)), __fmul_rn(z, z));
}

// np.einsum (optimize=False) remainder falls through DESCENDING for count=3:
// ((z*z') + y*y') + x*x'.  dist = ((-2*dot) + n_src) + n_dst.
__device__ __forceinline__ float dist_exact(float px, float py, float pz, float pw,
                                            float qx, float qy, float qz, float qn) {
    const float dot = __fadd_rn(
        __fadd_rn(__fmul_rn(pz, qz), __fmul_rn(py, qy)), __fmul_rn(px, qx));
    return __fadd_rn(__fadd_rn(__fmul_rn(dot, -2.0f), pw), qn);
}

// Order-preserving float -> u32 map (strictly monotone for all finite floats).
__device__ __forceinline__ unsigned omap(float f) {
    const unsigned u = __float_as_uint(f);
    return u ^ (((unsigned)((int)u >> 31)) | 0x80000000u);
}

extern "C" __global__ __launch_bounds__(THREADS, 8)
void knn_kernel(const float* __restrict__ verts, int* __restrict__ out)
{
    // Static LDS 22528 B. Grid 1024 = 4 blocks/CU x 8 waves = 32 waves/CU.
    __shared__ float vdump[NQB][NCH];                   // 16384 B (SHIFTED minima)
    __shared__ unsigned long long hbk[NQB][CAP];        //  4096 B (packed hit keys)
    __shared__ int cand[NQB][MAXC];                     //  2048 B

    const int t    = threadIdx.x;
    const int lane = t & 63;
    const int wv   = t >> 6;          // wave 0..7 (= its query)
    const int c    = t;               // half-chunk 0..511 (one per thread)
    const int qbase = blockIdx.x * NQB;

    // Register tile: 8 block queries as 4 PACKED PAIRS of folded -2*q coords
    // (-> v_pk_fma_f32 dual-FP32 in pass 1). qn is NOT kept: vdump stores
    // shifted minima; the per-query shift is re-applied by the owning wave.
    v2f qxp[4], qyp[4], qzp[4];
#pragma unroll
    for (int j = 0; j < 4; ++j) {
#pragma unroll
        for (int h = 0; h < 2; ++h) {
            const int qi = qbase + 2 * j + h;
            qxp[j][h] = -2.0f * verts[qi * 3 + 0];
            qyp[j][h] = -2.0f * verts[qi * 3 + 1];
            qzp[j][h] = -2.0f * verts[qi * 3 + 2];
        }
    }

    // ---------------- PASS 1: per-(half-chunk,query) shifted MIN ------------
    // Half-chunk c = { w*WIN + c*JPW + j : w<4, j<4 }: 12 consecutive floats
    // per window = 3 aligned float4 (48B-aligned base). NO barriers, NO LDS.
    // Packed math: splat point into v2f, 3 pk_fma per query pair; values are
    // bit-identical to the scalar fma version (IEEE fma per lane).
    v2f mnp[4];
#pragma unroll
    for (int j = 0; j < 4; ++j) mnp[j] = (v2f){INFINITY, INFINITY};

    auto pair8 = [&](float px, float py, float pz) {
        const float pw = norm3(px, py, pz);
        const v2f pxs = {px, px}, pys = {py, py}, pzs = {pz, pz}, pws = {pw, pw};
#pragma unroll
        for (int j = 0; j < 4; ++j) {
            const v2f d = __builtin_elementwise_fma(pxs, qxp[j],
                          __builtin_elementwise_fma(pys, qyp[j],
                          __builtin_elementwise_fma(pzs, qzp[j], pws)));
            mnp[j] = __builtin_elementwise_min(mnp[j], d);
        }
    };

#pragma unroll
    for (int w = 0; w < NWIN; ++w) {
        const float4* vp = (const float4*)(verts + (w * WIN + c * JPW) * 3);
        const float4 A = vp[0], B = vp[1], C = vp[2];
        pair8(A.x, A.y, A.z); pair8(A.w, B.x, B.y);
        pair8(B.z, B.w, C.x); pair8(C.y, C.z, C.w);
    }

#pragma unroll
    for (int j = 0; j < 4; ++j) {                       // shifted (no qn)
        vdump[2 * j + 0][c] = mnp[j].x;
        vdump[2 * j + 1][c] = mnp[j].y;
    }
    __syncthreads();
    // -------- From here on, EVERYTHING is wave-local (no barriers/atomics). --
    // Wave wv owns query wv. (Byte-identical to R22's back half.)

    const int qq = wv;
    const int qg2 = qbase + qq;
    const float qxe = verts[qg2 * 3 + 0];
    const float qye = verts[qg2 * 3 + 1];
    const float qze = verts[qg2 * 3 + 2];
    const float qne = norm3(qxe, qye, qze);

    // 8 stride-64 scalar LDS reads: conflict-free (lanes consecutive).
    float sv[8];
#pragma unroll
    for (int k = 0; k < 8; ++k) sv[k] = vdump[qq][k * 64 + lane];

    // ---- T' (shifted) = 20th smallest of 512 half-chunk minima via bitwise
    // binary search on order-mapped u32 (top 22 bits; low 10 filled with 1s —
    // overshoot <= 2^10 ulp, absorbed by MARGIN; only widens the candidate set).
    unsigned uv[8];
#pragma unroll
    for (int k = 0; k < 8; ++k) uv[k] = omap(sv[k]);
    unsigned A = 0;
#pragma unroll
    for (int b = 31; b >= 10; --b) {
        const unsigned cv = A | (1u << b);
        int cnt = 0;
#pragma unroll
        for (int k = 0; k < 8; ++k) cnt += __popcll(__ballot(uv[k] < cv));
        if (cnt <= KK - 1) A = cv;   // max A with count(< A) <= 19
    }
    A |= 0x3FFu;
    const float Tsh = ((A >> 31) ? __uint_as_float(A ^ 0x80000000u)
                                 : __uint_as_float(~A)) + MARGIN;  // shifted T
    const float T = Tsh + qne;                  // true-space T for exact test

    // ---- Candidate half-chunks via ballot compaction (no atomics) ----------
    int nc = 0;
#pragma unroll
    for (int k = 0; k < 8; ++k) {
        const bool pred = (sv[k] <= Tsh);
        const unsigned long long bal = __ballot(pred);
        const int rank = nc + __popcll(bal & ((1ULL << lane) - 1));
        if (pred && rank < MAXC) cand[qq][rank] = k * 64 + lane;
        nc += __popcll(bal);
    }
    nc = min(nc, MAXC);

    // ------- PASS 2 (sparse): 4 cands x 16 pts per u-step, 16 cands/group ---
    // sub = lane>>4 picks candidate; p = lane&15 -> point n = (p>>2)*WIN +
    // cc*JPW + (p&3)  (the half-chunk's true point set). 12 loads in flight.
    int hc = 0;                                 // hit count (wave-uniform)
    {
        const int sub = lane >> 4;
        const int p = lane & 15;
        const int nfix = (p >> 2) * WIN + (p & 3);
        for (int e0 = 0; e0 < nc; e0 += 16) {   // wave-uniform groups of 16
            float PX[4], PY[4], PZ[4]; int NN[4];
#pragma unroll
            for (int u = 0; u < 4; ++u) {       // 12 independent loads in flight
                const int e = e0 + 4 * u + sub;
                const int cc = cand[qq][e < nc ? e : 0];
                const int n = nfix + cc * JPW;
                NN[u] = n;
                PX[u] = verts[n * 3 + 0];
                PY[u] = verts[n * 3 + 1];
                PZ[u] = verts[n * 3 + 2];
            }
#pragma unroll
            for (int u = 0; u < 4; ++u) {
                const float pw = norm3(PX[u], PY[u], PZ[u]);
                const float d = dist_exact(PX[u], PY[u], PZ[u], pw,
                                           qxe, qye, qze, qne);
                const bool pred = ((e0 + 4 * u + sub) < nc) && (d <= T);
                // Ballot-compacted hit append (no atomics).
                const unsigned long long bal = __ballot(pred);
                const int rank = __popcll(bal & ((1ULL << lane) - 1));
                if (pred) {
                    const int slot = hc + rank;
                    if (slot < CAP)
                        hbk[qq][slot] = ((unsigned long long)omap(d) << 32)
                                      | (unsigned)NN[u];
                }
                hc += __popcll(bal);
            }
        }
    }

    // ------- Final: stable top-20 via rank selection (no sort chain) --------
    // rank = #{keys < mine}; unique keys => exact stable ascending (d, idx).
    {
        const int kc = min(hc, CAP);            // kc >= 20 guaranteed
        const unsigned long long mykey = (lane < kc) ? hbk[qq][lane] : ~0ULL;
        int rank = 0;
        for (int e = 0; e < kc; ++e)            // broadcast LDS reads, pipelined
            rank += (hbk[qq][e] < mykey) ? 1 : 0;
        if (lane < kc && rank < KK)
            out[(qbase + qq) * KK + rank] =
                (int)(unsigned)(mykey & 0xffffffffULL);
    }
}

extern "C" void kernel_launch(void* const* d_in, const int* in_sizes, int n_in,
                              void* d_out, int out_size, void* d_ws, size_t ws_size,
                              hipStream_t stream) {
    // d_in[0] = feats (unused). d_in[1] = vertices [4,8192,3] f32; batch 0 only.
    const float* verts = (const float*)d_in[1];
    int* out = (int*)d_out;
    knn_kernel<<<dim3(NPTS / NQB), dim3(THREADS), 0, stream>>>(verts, out);
}

// Round 24
// 20.592 us; speedup vs baseline: 1.1503x; 1.1503x over previous
//
#include <hip/hip_runtime.h>
#include <math.h>

#define KK 20
#define NPTS 8192
#define NQB 8               // queries per block (= 1 per wave)
#define QPL 8               // queries per lane (pass 1)
#define NCH 512             // half-chunks per query (16 pts: 4 windows x 4)
#define THREADS 512
#define WIN 2048
#define NWIN 4
#define JPW 4               // consecutive points per half-chunk per window
#define CAP 64              // hit buffer capacity per query
#define MAXC 64             // candidate-chunk list capacity per query
#define MARGIN 4e-3f        // >> 2*max|d_fast - d_exact| + T-search slack

// Exact (non-contracted) IEEE ops matching the NumPy reference bit-for-bit.
// np.sum (pairwise, n<8) accumulates ascending: (x^2 + y^2) + z^2.
__device__ __forceinline__ float norm3(float x, float y, float z) {
    return __fadd_rn(__fadd_rn(__fmul_rn(x, x), __fmul_rn(y, y)), __fmul_rn(z, z));
}

// np.einsum (optimize=False) remainder falls through DESCENDING for count=3:
// ((z*z') + y*y') + x*x'.  dist = ((-2*dot) + n_src) + n_dst.
__device__ __forceinline__ float dist_exact(float px, float py, float pz, float pw,
                                            float qx, float qy, float qz, float qn) {
    const float dot = __fadd_rn(
        __fadd_rn(__fmul_rn(pz, qz), __fmul_rn(py, qy)), __fmul_rn(px, qx));
    return __fadd_rn(__fadd_rn(__fmul_rn(dot, -2.0f), pw), qn);
}

// Order-preserving float -> u32 map (strictly monotone for all finite floats).
__device__ __forceinline__ unsigned omap(float f) {
    const unsigned u = __float_as_uint(f);
    return u ^ (((unsigned)((int)u >> 31)) | 0x80000000u);
}

extern "C" __global__ __launch_bounds__(THREADS, 8)
void knn_kernel(const float* __restrict__ verts, int* __restrict__ out)
{
    // Static LDS 22528 B. Grid 1024 = 4 blocks/CU x 8 waves = 32 waves/CU.
    __shared__ float vdump[NQB][NCH];                   // 16384 B (SHIFTED minima)
    __shared__ unsigned long long hbk[NQB][CAP];        //  4096 B (packed hit keys)
    __shared__ int cand[NQB][MAXC];                     //  2048 B

    const int t    = threadIdx.x;
    const int lane = t & 63;
    const int wv   = t >> 6;          // wave 0..7 (= its query)
    const int c    = t;               // half-chunk 0..511 (one per thread)
    const int qbase = blockIdx.x * NQB;

    // Register tile: all 8 block queries per lane, folded -2*q coords only
    // (qn is NOT kept: vdump stores shifted minima; shift re-applied later).
    float qx2[QPL], qy2[QPL], qz2[QPL];
#pragma unroll
    for (int i = 0; i < QPL; ++i) {
        qx2[i] = -2.0f * verts[(qbase + i) * 3 + 0];
        qy2[i] = -2.0f * verts[(qbase + i) * 3 + 1];
        qz2[i] = -2.0f * verts[(qbase + i) * 3 + 2];
    }

    // ---------------- PASS 1: per-(half-chunk,query) shifted MIN ------------
    // Half-chunk c = { w*WIN + c*JPW + j : w<4, j<4 }: 12 consecutive floats
    // per window = 3 aligned float4 (48B-aligned base). NO barriers, NO LDS.
    float mn[QPL];
#pragma unroll
    for (int i = 0; i < QPL; ++i) mn[i] = INFINITY;

    auto pair8 = [&](float px, float py, float pz) {
        const float pw = norm3(px, py, pz);
#pragma unroll
        for (int i = 0; i < QPL; ++i) {
            const float d = __builtin_fmaf(px, qx2[i],
                            __builtin_fmaf(py, qy2[i],
                            __builtin_fmaf(pz, qz2[i], pw)));
            mn[i] = fminf(mn[i], d);
        }
    };

#pragma unroll
    for (int w = 0; w < NWIN; ++w) {
        const float4* vp = (const float4*)(verts + (w * WIN + c * JPW) * 3);
        const float4 A = vp[0], B = vp[1], C = vp[2];
        pair8(A.x, A.y, A.z); pair8(A.w, B.x, B.y);
        pair8(B.z, B.w, C.x); pair8(C.y, C.z, C.w);
    }

#pragma unroll
    for (int i = 0; i < QPL; ++i) vdump[i][c] = mn[i];   // shifted (no qn)

    // Owning-wave query reload: independent global loads issued BEFORE the
    // barrier so their latency hides under the LDS drain.
    const int qq = wv;
    const int qg2 = qbase + qq;
    const float qxe = verts[qg2 * 3 + 0];
    const float qye = verts[qg2 * 3 + 1];
    const float qze = verts[qg2 * 3 + 2];
    const float qne = norm3(qxe, qye, qze);

    __syncthreads();
    // -------- From here on, EVERYTHING is wave-local (no barriers/atomics). --
    // Wave wv owns query wv. Lane holds shifted minima of chunks {64k+lane}.

    // 8 stride-64 scalar LDS reads: conflict-free (lanes consecutive).
    float sv[8];
#pragma unroll
    for (int k = 0; k < 8; ++k) sv[k] = vdump[qq][k * 64 + lane];

    // ---- T' via lane-min domination + 1-ballot bitwise binary search -------
    // lmin = min of this lane's 8 values. For any x, count over lane-minima
    // <= count over all 512 => 20th-order-stat(lane minima) >= 20th(all 512):
    // threshold only loosens (completeness preserved; exact rescan decides).
    // Search top 22 bits, fill low 10 with 1s (further loosening only).
    const float m01 = fminf(sv[0], sv[1]), m23 = fminf(sv[2], sv[3]);
    const float m45 = fminf(sv[4], sv[5]), m67 = fminf(sv[6], sv[7]);
    const float lmin = fminf(fminf(m01, m23), fminf(m45, m67));
    const unsigned ul = omap(lmin);
    unsigned A = 0;
#pragma unroll
    for (int b = 31; b >= 10; --b) {
        const unsigned cv = A | (1u << b);
        if (__popcll(__ballot(ul < cv)) <= KK - 1) A = cv;  // max A: count(<A)<=19
    }
    A |= 0x3FFu;
    const float Tsh = ((A >> 31) ? __uint_as_float(A ^ 0x80000000u)
                                 : __uint_as_float(~A)) + MARGIN;  // shifted T
    const float T = Tsh + qne;                  // true-space T for exact test

    // ---- Candidate half-chunks via ballot compaction (no atomics) ----------
    int nc = 0;
#pragma unroll
    for (int k = 0; k < 8; ++k) {
        const bool pred = (sv[k] <= Tsh);
        const unsigned long long bal = __ballot(pred);
        const int rank = nc + __popcll(bal & ((1ULL << lane) - 1));
        if (pred && rank < MAXC) cand[qq][rank] = k * 64 + lane;
        nc += __popcll(bal);
    }
    nc = min(nc, MAXC);

    // ------- PASS 2 (sparse): 4 cands x 16 pts per u-step, 16 cands/group ---
    // sub = lane>>4 picks candidate; p = lane&15 -> point n = (p>>2)*WIN +
    // cc*JPW + (p&3)  (the half-chunk's true point set). 12 loads in flight.
    int hc = 0;                                 // hit count (wave-uniform)
    {
        const int sub = lane >> 4;
        const int p = lane & 15;
        const int nfix = (p >> 2) * WIN + (p & 3);
        for (int e0 = 0; e0 < nc; e0 += 16) {   // wave-uniform groups of 16
            float PX[4], PY[4], PZ[4]; int NN[4];
#pragma unroll
            for (int u = 0; u < 4; ++u) {       // 12 independent loads in flight
                const int e = e0 + 4 * u + sub;
                const int cc = cand[qq][e < nc ? e : 0];
                const int n = nfix + cc * JPW;
                NN[u] = n;
                PX[u] = verts[n * 3 + 0];
                PY[u] = verts[n * 3 + 1];
                PZ[u] = verts[n * 3 + 2];
            }
#pragma unroll
            for (int u = 0; u < 4; ++u) {
                const float pw = norm3(PX[u], PY[u], PZ[u]);
                const float d = dist_exact(PX[u], PY[u], PZ[u], pw,
                                           qxe, qye, qze, qne);
                const bool pred = ((e0 + 4 * u + sub) < nc) && (d <= T);
                // Ballot-compacted hit append (no atomics).
                const unsigned long long bal = __ballot(pred);
                const int rank = __popcll(bal & ((1ULL << lane) - 1));
                if (pred) {
                    const int slot = hc + rank;
                    if (slot < CAP)
                        hbk[qq][slot] = ((unsigned long long)omap(d) << 32)
                                      | (unsigned)NN[u];
                }
                hc += __popcll(bal);
            }
        }
    }

    // ------- Final: stable top-20 via rank selection (no sort chain) --------
    // rank = #{keys < mine}; unique keys => exact stable ascending (d, idx).
    {
        const int kc = min(hc, CAP);            // kc >= 20 guaranteed
        const unsigned long long mykey = (lane < kc) ? hbk[qq][lane] : ~0ULL;
        int rank = 0;
        for (int e = 0; e < kc; ++e)            // broadcast LDS reads, pipelined
            rank += (hbk[qq][e] < mykey) ? 1 : 0;
        if (lane < kc && rank < KK)
            out[(qbase + qq) * KK + rank] =
                (int)(unsigned)(mykey & 0xffffffffULL);
    }
}

extern "C" void kernel_launch(void* const* d_in, const int* in_sizes, int n_in,
                              void* d_out, int out_size, void* d_ws, size_t ws_size,
                              hipStream_t stream) {
    // d_in[0] = feats (unused). d_in[1] = vertices [4,8192,3] f32; batch 0 only.
    const float* verts = (const float*)d_in[1];
    int* out = (int*)d_out;
    knn_kernel<<<dim3(NPTS / NQB), dim3(THREADS), 0, stream>>>(verts, out);
}